// Round 1
// baseline (2960.915 us; speedup 1.0000x reference)
//
#include <hip/hip_runtime.h>
#include <cstdint>
#include <cstddef>

// ---------------------------------------------------------------------------
// conv1: x[16,3,256,256] -> y[16,64,128,128], k=4 s=2 p=1, ReLU
// One thread per output pixel, all 64 oc in a loop; weights (3072 f) in LDS.
// ---------------------------------------------------------------------------
__global__ __launch_bounds__(256) void conv1_kernel(
    const float* __restrict__ x, const float* __restrict__ w,
    const float* __restrict__ bias, float* __restrict__ y)
{
  __shared__ __align__(16) float wl[64 * 48];
  __shared__ float bl[64];
  const int tid = threadIdx.x;
  for (int i = tid; i < 64 * 48; i += 256) wl[i] = w[i];
  if (tid < 64) bl[tid] = bias[tid];
  __syncthreads();
  const int n  = blockIdx.y;
  const int oh = blockIdx.x * 2 + (tid >> 7);
  const int ow = tid & 127;
  const float* xb = x + (size_t)n * 3 * 65536;
  const int ih0 = oh * 2 - 1, iw0 = ow * 2 - 1;
  float xin[48];
#pragma unroll
  for (int ic = 0; ic < 3; ++ic)
#pragma unroll
    for (int kh = 0; kh < 4; ++kh) {
      int ih = ih0 + kh;
      bool rok = (unsigned)ih < 256u;
#pragma unroll
      for (int kw = 0; kw < 4; ++kw) {
        int iw = iw0 + kw;
        xin[ic * 16 + kh * 4 + kw] =
            (rok && (unsigned)iw < 256u) ? xb[ic * 65536 + ih * 256 + iw] : 0.f;
      }
    }
  float* yb = y + (size_t)n * 64 * 16384 + oh * 128 + ow;
  for (int oc = 0; oc < 64; ++oc) {
    float acc = bl[oc];
    const float* wo = &wl[oc * 48];
#pragma unroll
    for (int j = 0; j < 48; ++j) acc = fmaf(wo[j], xin[j], acc);
    yb[(size_t)oc * 16384] = fmaxf(acc, 0.f);
  }
}

// ---------------------------------------------------------------------------
// conv_s2: k=4 s=2 p=1 direct conv as implicit GEMM.
// Block: 64 oc x (8x8 out pixels) for one n. Thread: 4 oc x 4 pixels.
// Wl[k][oc] transposed+padded(68) for float4 A reads; X patch [4ic][18][19].
// ---------------------------------------------------------------------------
template <int CIN, int HIN, int COUT, bool RELU>
__global__ __launch_bounds__(256) void conv_s2(
    const float* __restrict__ x, const float* __restrict__ w,
    const float* __restrict__ bias, float* __restrict__ y)
{
  constexpr int HOUT = HIN / 2;
  constexpr int TILES = HOUT / 8;
  __shared__ __align__(16) float Wl[64 * 68];
  __shared__ __align__(16) float Xl[4 * 342];
  __shared__ float bl[64];
  const int tid = threadIdx.x;
  const int tx = tid & 15, ty = tid >> 4;
  const int oh0 = (blockIdx.x / TILES) * 8, ow0 = (blockIdx.x % TILES) * 8;
  const int oc0 = blockIdx.y * 64;
  const int n = blockIdx.z;
  if (tid < 64) bl[tid] = bias[oc0 + tid];
  const float* xn = x + (size_t)n * CIN * (HIN * HIN);
  float acc[4][4] = {};
  int xoff[4];
#pragma unroll
  for (int q = 0; q < 4; ++q) {
    int p = tx + 16 * q;
    xoff[q] = (2 * (p >> 3)) * 19 + 2 * (p & 7);
  }
  const int ihb = 2 * oh0 - 1, iwb = 2 * ow0 - 1;
  for (int ic0 = 0; ic0 < CIN; ic0 += 4) {
    __syncthreads();
    // stage weights: 64 oc x 64 k (k = ic_l*16 + kh*4 + kw), transposed
#pragma unroll
    for (int it = 0; it < 4; ++it) {
      int i = tid + it * 256;
      int oc_l = i >> 4, kq = i & 15;
      const float* wp = &w[((size_t)(oc0 + oc_l) * CIN + ic0) * 16 + kq * 4];
      float4 wv = *(const float4*)wp;
      Wl[(kq * 4 + 0) * 68 + oc_l] = wv.x;
      Wl[(kq * 4 + 1) * 68 + oc_l] = wv.y;
      Wl[(kq * 4 + 2) * 68 + oc_l] = wv.z;
      Wl[(kq * 4 + 3) * 68 + oc_l] = wv.w;
    }
    // stage input patch: 4 ic x 18 x 19 (rows 2*oh0-1 .. +17), zero-padded
    for (int i = tid; i < 4 * 342; i += 256) {
      int ic_l = i / 342, rem = i - ic_l * 342;
      int rr = rem / 19, cc = rem - rr * 19;
      int ih = ihb + rr, iw = iwb + cc;
      float v = 0.f;
      if ((unsigned)ih < (unsigned)HIN && (unsigned)iw < (unsigned)HIN)
        v = xn[(size_t)(ic0 + ic_l) * (HIN * HIN) + ih * HIN + iw];
      Xl[i] = v;
    }
    __syncthreads();
#pragma unroll
    for (int ic_l = 0; ic_l < 4; ++ic_l) {
#pragma unroll
      for (int tap = 0; tap < 16; ++tap) {
        const int k = ic_l * 16 + tap;
        const int kh = tap >> 2, kw = tap & 3;
        float4 a = *(const float4*)&Wl[k * 68 + ty * 4];
        const int base = ic_l * 342 + kh * 19 + kw;
        float av[4] = {a.x, a.y, a.z, a.w};
        float bb[4] = {Xl[base + xoff[0]], Xl[base + xoff[1]],
                       Xl[base + xoff[2]], Xl[base + xoff[3]]};
#pragma unroll
        for (int i2 = 0; i2 < 4; ++i2)
#pragma unroll
          for (int q = 0; q < 4; ++q)
            acc[i2][q] = fmaf(av[i2], bb[q], acc[i2][q]);
      }
    }
  }
  float* yn = y + ((size_t)n * COUT + oc0) * (HOUT * HOUT);
#pragma unroll
  for (int i = 0; i < 4; ++i) {
    float bbias = bl[ty * 4 + i];
#pragma unroll
    for (int q = 0; q < 4; ++q) {
      int p = tx + 16 * q;
      int u = p >> 3, v = p & 7;
      float vv = acc[i][q] + bbias;
      if (RELU) vv = fmaxf(vv, 0.f);
      yn[(size_t)(ty * 4 + i) * (HOUT * HOUT) + (oh0 + u) * HOUT + (ow0 + v)] = vv;
    }
  }
}

// ---------------------------------------------------------------------------
// deconv_s2: ConvTranspose2d(k=4,s=2,p=1) == per-output-parity 2x2 s1 conv.
// y[r][c] = sum_{kh',kw',ic} w[oc][ic][2kh'+pr][2kw'+pc] *
//           x[r/2 + kh' - 1 + pr][c/2 + kw' - 1 + pc]
// Block: 64 oc x (8x8 out pixels); wave = one parity (weight read uniform).
// Thread: 4 oc x 4 pixels (a column of its wave's 4x4 parity plane).
// ---------------------------------------------------------------------------
template <int CIN, int HIN, int COUT, bool RELU>
__global__ __launch_bounds__(256) void deconv_s2(
    const float* __restrict__ x, const float* __restrict__ w,
    const float* __restrict__ bias, float* __restrict__ y)
{
  constexpr int HOUT = HIN * 2;
  constexpr int TILES = HOUT / 8;
  __shared__ __align__(16) float Wl[16 * 4 * 68];  // [k][par][oc+pad]
  __shared__ __align__(16) float Xl[4 * 48];       // [ic][6 rows][8 cols]
  __shared__ float bl[64];
  const int tid = threadIdx.x;
  const int wvid = tid >> 6;
  const int pr = wvid >> 1, pc = wvid & 1;
  const int lane = tid & 63;
  const int ty = lane >> 2, txv = lane & 3;
  const int r0 = (blockIdx.x / TILES) * 8, c0 = (blockIdx.x % TILES) * 8;
  const int a0 = r0 >> 1, b0 = c0 >> 1;
  const int oc0 = blockIdx.y * 64;
  const int n = blockIdx.z;
  if (tid < 64) bl[tid] = bias[oc0 + tid];
  const float* xn = x + (size_t)n * CIN * (HIN * HIN);
  float acc[4][4] = {};  // [oc i][u]
  for (int ic0 = 0; ic0 < CIN; ic0 += 4) {
    __syncthreads();
    // stage weights: 64 oc x 4 ic x 16 taps -> Wl[k][par][oc]
#pragma unroll
    for (int it = 0; it < 4; ++it) {
      int i = tid + it * 256;
      int oc_l = i >> 4, r = i & 15;
      int ic_l = r >> 2, kh = r & 3;
      const float* wp = &w[((size_t)(oc0 + oc_l) * CIN + ic0 + ic_l) * 16 + kh * 4];
      float4 wv4 = *(const float4*)wp;
      float wa[4] = {wv4.x, wv4.y, wv4.z, wv4.w};
#pragma unroll
      for (int kw = 0; kw < 4; ++kw) {
        int kk = ic_l * 4 + (kh >> 1) * 2 + (kw >> 1);
        int par = (kh & 1) * 2 + (kw & 1);
        Wl[(kk * 4 + par) * 68 + oc_l] = wa[kw];
      }
    }
    // stage input patch: 4 ic x rows[a0-1..a0+4] x cols[b0-1..b0+4]
    for (int i = tid; i < 4 * 48; i += 256) {
      int ic_l = i / 48, rem = i - ic_l * 48;
      int rr = rem >> 3, cc = rem & 7;
      float v = 0.f;
      if (cc < 6) {
        int ih = a0 - 1 + rr, iw = b0 - 1 + cc;
        if ((unsigned)ih < (unsigned)HIN && (unsigned)iw < (unsigned)HIN)
          v = xn[(size_t)(ic0 + ic_l) * (HIN * HIN) + ih * HIN + iw];
      }
      Xl[i] = v;
    }
    __syncthreads();
#pragma unroll
    for (int ic_l = 0; ic_l < 4; ++ic_l) {
#pragma unroll
      for (int kk = 0; kk < 4; ++kk) {
        const int khp = kk >> 1, kwp = kk & 1;
        const int k = ic_l * 4 + kk;
        float4 a = *(const float4*)&Wl[(k * 4 + pr * 2 + pc) * 68 + ty * 4];
        const int xb = ic_l * 48 + (khp + pr) * 8 + txv + kwp + pc;
        float av[4] = {a.x, a.y, a.z, a.w};
        float bb[4] = {Xl[xb], Xl[xb + 8], Xl[xb + 16], Xl[xb + 24]};
#pragma unroll
        for (int i2 = 0; i2 < 4; ++i2)
#pragma unroll
          for (int u = 0; u < 4; ++u)
            acc[i2][u] = fmaf(av[i2], bb[u], acc[i2][u]);
      }
    }
  }
  float* yn = y + ((size_t)n * COUT + oc0) * (HOUT * HOUT);
#pragma unroll
  for (int i = 0; i < 4; ++i) {
    float bbias = bl[ty * 4 + i];
#pragma unroll
    for (int u = 0; u < 4; ++u) {
      float vv = acc[i][u] + bbias;
      if (RELU) vv = fmaxf(vv, 0.f);
      yn[(size_t)(ty * 4 + i) * (HOUT * HOUT) +
         (size_t)(r0 + 2 * u + pr) * HOUT + (c0 + 2 * txv + pc)] = vv;
    }
  }
}

// ---------------------------------------------------------------------------
// vq_kernel: fused scores GEMM + running argmax.
// Block: 32 tokens x 2048 codes (split chosen by blockIdx%8 so each XCD's L2
// caches one 2MB codebook slice). Thread (8x32): 4 tokens x 4 codes.
// Tl[256k][32tok] staged once; Bl[64k][128code] per K-chunk. Both float4 reads.
// ---------------------------------------------------------------------------
__global__ __launch_bounds__(256) void vq_kernel(
    const float* __restrict__ feat, const float* __restrict__ cb,
    float* __restrict__ pscore, int* __restrict__ pidx)
{
  __shared__ __align__(16) float Tl[256 * 32];
  __shared__ __align__(16) float Bl[64 * 128];
  const int tid = threadIdx.x;
  const int tx = tid & 7, ty = tid >> 3;
  const int blk = blockIdx.x;
  const int split = (blk & 7) >> 1;
  const int tb = ((blk >> 3) << 1) | (blk & 1);
  const int b = tb >> 5, t0 = (tb & 31) * 32;
  const float* fb = feat + (size_t)b * 256 * 1024 + t0;
  {
    const int c = tid;
#pragma unroll
    for (int u = 0; u < 8; ++u) {
      float4 v = *(const float4*)&fb[(size_t)c * 1024 + u * 4];
      *(float4*)&Tl[c * 32 + u * 4] = v;
    }
  }
  float best[4] = {-3.4e38f, -3.4e38f, -3.4e38f, -3.4e38f};
  int bidx[4] = {0, 0, 0, 0};
  const int cbase = split * 2048;
  for (int ct = 0; ct < 16; ++ct) {
    float acc[4][4] = {};  // [code i][tok e]
    for (int kc0 = 0; kc0 < 256; kc0 += 64) {
      __syncthreads();
      {
        int code_l = tid >> 1, cq = tid & 1;
        const float* cbp = cb + ((size_t)(cbase + ct * 128 + code_l)) * 256 + kc0;
#pragma unroll
        for (int j = 0; j < 8; ++j) {
          int f = cq * 8 + j;
          float4 v = *(const float4*)&cbp[f * 4];
          Bl[(f * 4 + 0) * 128 + code_l] = v.x;
          Bl[(f * 4 + 1) * 128 + code_l] = v.y;
          Bl[(f * 4 + 2) * 128 + code_l] = v.z;
          Bl[(f * 4 + 3) * 128 + code_l] = v.w;
        }
      }
      __syncthreads();
#pragma unroll 4
      for (int kc = 0; kc < 64; ++kc) {
        float4 a = *(const float4*)&Tl[(kc0 + kc) * 32 + tx * 4];
        float4 bv = *(const float4*)&Bl[kc * 128 + ty * 4];
        float av[4] = {a.x, a.y, a.z, a.w};
        float bb[4] = {bv.x, bv.y, bv.z, bv.w};
#pragma unroll
        for (int i2 = 0; i2 < 4; ++i2)
#pragma unroll
          for (int e = 0; e < 4; ++e)
            acc[i2][e] = fmaf(bb[i2], av[e], acc[i2][e]);
      }
    }
#pragma unroll
    for (int i2 = 0; i2 < 4; ++i2) {
      int ci = cbase + ct * 128 + ty * 4 + i2;
#pragma unroll
      for (int e = 0; e < 4; ++e) {
        if (acc[i2][e] > best[e]) { best[e] = acc[i2][e]; bidx[e] = ci; }
      }
    }
  }
  __syncthreads();
  float* Rs = Bl;                 // [32 tok][32 ty]
  int* Ri = (int*)&Bl[1024];
#pragma unroll
  for (int e = 0; e < 4; ++e) {
    Rs[(tx * 4 + e) * 32 + ty] = best[e];
    Ri[(tx * 4 + e) * 32 + ty] = bidx[e];
  }
  __syncthreads();
  if (tid < 32) {
    float bs = -3.4e38f;
    int bi = 0;
#pragma unroll
    for (int t = 0; t < 32; ++t) {
      float s = Rs[tid * 32 + t];
      int ii = Ri[tid * 32 + t];
      if (s > bs || (s == bs && ii < bi)) { bs = s; bi = ii; }
    }
    int gt = b * 1024 + t0 + tid;
    pscore[split * 16384 + gt] = bs;
    pidx[split * 16384 + gt] = bi;
  }
}

// ---------------------------------------------------------------------------
// gather_kernel: merge 4 split-partials (strict > keeps lowest split =>
// correct first-max tie-break), write float indices to d_out, build q[b][c][t].
// ---------------------------------------------------------------------------
__global__ __launch_bounds__(256) void gather_kernel(
    const float* __restrict__ cb, const float* __restrict__ pscore,
    const int* __restrict__ pidx, float* __restrict__ q,
    float* __restrict__ idx_out)
{
  __shared__ int sidx[64];
  const int tid = threadIdx.x;
  const int blk = blockIdx.x;
  const int b = blk >> 4, t0 = (blk & 15) * 64;
  if (tid < 64) {
    int gt = b * 1024 + t0 + tid;
    float bs = -3.4e38f;
    int bi = 0;
#pragma unroll
    for (int s = 0; s < 4; ++s) {
      float v = pscore[s * 16384 + gt];
      int ii = pidx[s * 16384 + gt];
      if (v > bs) { bs = v; bi = ii; }
    }
    sidx[tid] = bi;
    idx_out[gt] = (float)bi;
  }
  __syncthreads();
  const int lane = tid & 63, cg = tid >> 6;
  const int code = sidx[lane];
  const float* src = cb + (size_t)code * 256;
  float* dst = q + (size_t)b * 256 * 1024 + t0 + lane;
#pragma unroll
  for (int cc = 0; cc < 64; ++cc) {
    int c = cg * 64 + cc;
    dst[(size_t)c * 1024] = src[c];
  }
}

// ---------------------------------------------------------------------------
// deconv3: [16,64,128,128] -> recon [16,3,256,256] (no ReLU). Direct, one
// thread per output pixel computing all 3 oc; weights parity-packed in LDS.
// ---------------------------------------------------------------------------
__global__ __launch_bounds__(256) void deconv3_kernel(
    const float* __restrict__ x, const float* __restrict__ w,
    const float* __restrict__ bias, float* __restrict__ y)
{
  __shared__ __align__(16) float wl[4 * 3 * 64 * 4];  // [par][oc][ic][kidx]
  const int tid = threadIdx.x;
  for (int i = tid; i < 3072; i += 256) {
    int oc = i >> 10, r = i & 1023, ic = r >> 4, tap = r & 15;
    int kh = tap >> 2, kw = tap & 3;
    int par = (kh & 1) * 2 + (kw & 1);
    int kidx = (kh >> 1) * 2 + (kw >> 1);
    wl[((par * 3 + oc) * 64 + ic) * 4 + kidx] = w[i];
  }
  __syncthreads();
  const int r = blockIdx.x, n = blockIdx.y, c = tid;
  const int pr = r & 1, pc = c & 1, par = pr * 2 + pc;
  const int a = r >> 1, bcol = c >> 1;
  const int ih0 = a - 1 + pr, iw0 = bcol - 1 + pc;
  const bool hv0 = (unsigned)ih0 < 128u, hv1 = (unsigned)(ih0 + 1) < 128u;
  const bool wv0 = (unsigned)iw0 < 128u, wv1 = (unsigned)(iw0 + 1) < 128u;
  const float* xn = x + (size_t)n * 64 * 16384;
  float acc0 = bias[0], acc1 = bias[1], acc2 = bias[2];
  const float* wp = &wl[par * 768];
  for (int ic = 0; ic < 64; ++ic) {
    const float* xr = xn + ic * 16384;
    float x00 = (hv0 && wv0) ? xr[ih0 * 128 + iw0] : 0.f;
    float x01 = (hv0 && wv1) ? xr[ih0 * 128 + iw0 + 1] : 0.f;
    float x10 = (hv1 && wv0) ? xr[(ih0 + 1) * 128 + iw0] : 0.f;
    float x11 = (hv1 && wv1) ? xr[(ih0 + 1) * 128 + iw0 + 1] : 0.f;
    float4 w0 = *(const float4*)&wp[(0 * 64 + ic) * 4];
    float4 w1 = *(const float4*)&wp[(1 * 64 + ic) * 4];
    float4 w2 = *(const float4*)&wp[(2 * 64 + ic) * 4];
    acc0 = fmaf(w0.x, x00, fmaf(w0.y, x01, fmaf(w0.z, x10, fmaf(w0.w, x11, acc0))));
    acc1 = fmaf(w1.x, x00, fmaf(w1.y, x01, fmaf(w1.z, x10, fmaf(w1.w, x11, acc1))));
    acc2 = fmaf(w2.x, x00, fmaf(w2.y, x01, fmaf(w2.z, x10, fmaf(w2.w, x11, acc2))));
  }
  float* yn = y + (size_t)n * 3 * 65536;
  yn[0 * 65536 + r * 256 + c] = acc0;
  yn[1 * 65536 + r * 256 + c] = acc1;
  yn[2 * 65536 + r * 256 + c] = acc2;
}

// ---------------------------------------------------------------------------
extern "C" void kernel_launch(void* const* d_in, const int* in_sizes, int n_in,
                              void* d_out, int out_size, void* d_ws, size_t ws_size,
                              hipStream_t stream)
{
  const float* x   = (const float*)d_in[0];
  const float* ew1 = (const float*)d_in[1];
  const float* eb1 = (const float*)d_in[2];
  const float* ew2 = (const float*)d_in[3];
  const float* eb2 = (const float*)d_in[4];
  const float* ew3 = (const float*)d_in[5];
  const float* eb3 = (const float*)d_in[6];
  const float* cb  = (const float*)d_in[7];
  const float* dw1 = (const float*)d_in[8];
  const float* db1 = (const float*)d_in[9];
  const float* dw2 = (const float*)d_in[10];
  const float* db2 = (const float*)d_in[11];
  const float* dw3 = (const float*)d_in[12];
  const float* db3 = (const float*)d_in[13];

  float* recon = (float*)d_out;                    // [16,3,256,256]
  float* idxf  = (float*)d_out + 3145728;          // [16,1024] as float

  char* ws = (char*)d_ws;
  // liveness-aliased workspace (total 100,663,296 B):
  float* h1   = (float*)ws;                        // [0, 67.1MB)   conv1 out
  float* h2   = (float*)(ws + 67108864);           // [67.1, 100.7) conv2 out / d1
  float* feat = (float*)ws;                        // [0, 16.8MB)   conv3 out (h1 dead)
  float* psc  = (float*)(ws + 16777216);           // [16.8, 17.05) vq partial scores
  int*   pid  = (int*)  (ws + 17039360);           // [17.05,17.3)  vq partial idx
  float* q    = (float*)(ws + 33554432);           // [33.5, 50.3)  quantized (feat dead after vq)
  float* d1   = h2;                                // deconv1 out (h2 dead)
  float* d2   = (float*)ws;                        // deconv2 out (q/psc dead)

  conv1_kernel<<<dim3(64, 16), 256, 0, stream>>>(x, ew1, eb1, h1);
  conv_s2<64, 128, 128, true><<<dim3(64, 2, 16), 256, 0, stream>>>(h1, ew2, eb2, h2);
  conv_s2<128, 64, 256, false><<<dim3(16, 4, 16), 256, 0, stream>>>(h2, ew3, eb3, feat);
  vq_kernel<<<dim3(2048), 256, 0, stream>>>(feat, cb, psc, pid);
  gather_kernel<<<dim3(256), 256, 0, stream>>>(cb, psc, pid, q, idxf);
  deconv_s2<256, 32, 128, true><<<dim3(64, 2, 16), 256, 0, stream>>>(q, dw1, db1, d1);
  deconv_s2<128, 64, 64, true><<<dim3(256, 1, 16), 256, 0, stream>>>(d1, dw2, db2, d2);
  deconv3_kernel<<<dim3(256, 16), 256, 0, stream>>>(d2, dw3, db3, recon);
}

// Round 2
// 2309.617 us; speedup vs baseline: 1.2820x; 1.2820x over previous
//
#include <hip/hip_runtime.h>
#include <cstdint>
#include <cstddef>

typedef __attribute__((ext_vector_type(8))) short short8;
typedef __attribute__((ext_vector_type(4))) float f32x4;

// bf16 helpers (RNE)
__device__ __forceinline__ short f2bf(float x) {
  union { float f; unsigned u; } a; a.f = x;
  unsigned r = a.u + 0x7fff + ((a.u >> 16) & 1);
  return (short)(r >> 16);
}
__device__ __forceinline__ float bf2f(short s) {
  union { unsigned u; float f; } a;
  a.u = ((unsigned)(unsigned short)s) << 16; return a.f;
}

// async global->LDS, 16B per lane; lds dest = uniform base + lane*16
__device__ __forceinline__ void ld16(const void* g, void* l) {
  __builtin_amdgcn_global_load_lds(
      (const __attribute__((address_space(1))) unsigned int*)g,
      (__attribute__((address_space(3))) unsigned int*)l, 16, 0, 0);
}

// ---------------------------------------------------------------------------
// conv1: x[16,3,256,256] -> y[16,64,128,128], k=4 s=2 p=1, ReLU
// ---------------------------------------------------------------------------
__global__ __launch_bounds__(256) void conv1_kernel(
    const float* __restrict__ x, const float* __restrict__ w,
    const float* __restrict__ bias, float* __restrict__ y)
{
  __shared__ __align__(16) float wl[64 * 48];
  __shared__ float bl[64];
  const int tid = threadIdx.x;
  for (int i = tid; i < 64 * 48; i += 256) wl[i] = w[i];
  if (tid < 64) bl[tid] = bias[tid];
  __syncthreads();
  const int n  = blockIdx.y;
  const int oh = blockIdx.x * 2 + (tid >> 7);
  const int ow = tid & 127;
  const float* xb = x + (size_t)n * 3 * 65536;
  const int ih0 = oh * 2 - 1, iw0 = ow * 2 - 1;
  float xin[48];
#pragma unroll
  for (int ic = 0; ic < 3; ++ic)
#pragma unroll
    for (int kh = 0; kh < 4; ++kh) {
      int ih = ih0 + kh;
      bool rok = (unsigned)ih < 256u;
#pragma unroll
      for (int kw = 0; kw < 4; ++kw) {
        int iw = iw0 + kw;
        xin[ic * 16 + kh * 4 + kw] =
            (rok && (unsigned)iw < 256u) ? xb[ic * 65536 + ih * 256 + iw] : 0.f;
      }
    }
  float* yb = y + (size_t)n * 64 * 16384 + oh * 128 + ow;
  for (int oc = 0; oc < 64; ++oc) {
    float acc = bl[oc];
    const float* wo = &wl[oc * 48];
#pragma unroll
    for (int j = 0; j < 48; ++j) acc = fmaf(wo[j], xin[j], acc);
    yb[(size_t)oc * 16384] = fmaxf(acc, 0.f);
  }
}

// ---------------------------------------------------------------------------
// conv_s2: k=4 s=2 p=1 implicit GEMM (fp32). Block 64oc x 8x8 px; thread 4x4.
// ---------------------------------------------------------------------------
template <int CIN, int HIN, int COUT, bool RELU>
__global__ __launch_bounds__(256) void conv_s2(
    const float* __restrict__ x, const float* __restrict__ w,
    const float* __restrict__ bias, float* __restrict__ y)
{
  constexpr int HOUT = HIN / 2;
  constexpr int TILES = HOUT / 8;
  __shared__ __align__(16) float Wl[64 * 68];
  __shared__ __align__(16) float Xl[4 * 342];
  __shared__ float bl[64];
  const int tid = threadIdx.x;
  const int tx = tid & 15, ty = tid >> 4;
  const int oh0 = (blockIdx.x / TILES) * 8, ow0 = (blockIdx.x % TILES) * 8;
  const int oc0 = blockIdx.y * 64;
  const int n = blockIdx.z;
  if (tid < 64) bl[tid] = bias[oc0 + tid];
  const float* xn = x + (size_t)n * CIN * (HIN * HIN);
  float acc[4][4] = {};
  int xoff[4];
#pragma unroll
  for (int q = 0; q < 4; ++q) {
    int p = tx + 16 * q;
    xoff[q] = (2 * (p >> 3)) * 19 + 2 * (p & 7);
  }
  const int ihb = 2 * oh0 - 1, iwb = 2 * ow0 - 1;
  for (int ic0 = 0; ic0 < CIN; ic0 += 4) {
    __syncthreads();
#pragma unroll
    for (int it = 0; it < 4; ++it) {
      int i = tid + it * 256;
      int oc_l = i >> 4, kq = i & 15;
      const float* wp = &w[((size_t)(oc0 + oc_l) * CIN + ic0) * 16 + kq * 4];
      float4 wv = *(const float4*)wp;
      Wl[(kq * 4 + 0) * 68 + oc_l] = wv.x;
      Wl[(kq * 4 + 1) * 68 + oc_l] = wv.y;
      Wl[(kq * 4 + 2) * 68 + oc_l] = wv.z;
      Wl[(kq * 4 + 3) * 68 + oc_l] = wv.w;
    }
    for (int i = tid; i < 4 * 342; i += 256) {
      int ic_l = i / 342, rem = i - ic_l * 342;
      int rr = rem / 19, cc = rem - rr * 19;
      int ih = ihb + rr, iw = iwb + cc;
      float v = 0.f;
      if ((unsigned)ih < (unsigned)HIN && (unsigned)iw < (unsigned)HIN)
        v = xn[(size_t)(ic0 + ic_l) * (HIN * HIN) + ih * HIN + iw];
      Xl[i] = v;
    }
    __syncthreads();
#pragma unroll
    for (int ic_l = 0; ic_l < 4; ++ic_l) {
#pragma unroll
      for (int tap = 0; tap < 16; ++tap) {
        const int k = ic_l * 16 + tap;
        const int kh = tap >> 2, kw = tap & 3;
        float4 a = *(const float4*)&Wl[k * 68 + ty * 4];
        const int base = ic_l * 342 + kh * 19 + kw;
        float av[4] = {a.x, a.y, a.z, a.w};
        float bb[4] = {Xl[base + xoff[0]], Xl[base + xoff[1]],
                       Xl[base + xoff[2]], Xl[base + xoff[3]]};
#pragma unroll
        for (int i2 = 0; i2 < 4; ++i2)
#pragma unroll
          for (int q = 0; q < 4; ++q)
            acc[i2][q] = fmaf(av[i2], bb[q], acc[i2][q]);
      }
    }
  }
  float* yn = y + ((size_t)n * COUT + oc0) * (HOUT * HOUT);
#pragma unroll
  for (int i = 0; i < 4; ++i) {
    float bbias = bl[ty * 4 + i];
#pragma unroll
    for (int q = 0; q < 4; ++q) {
      int p = tx + 16 * q;
      int u = p >> 3, v = p & 7;
      float vv = acc[i][q] + bbias;
      if (RELU) vv = fmaxf(vv, 0.f);
      yn[(size_t)(ty * 4 + i) * (HOUT * HOUT) + (oh0 + u) * HOUT + (ow0 + v)] = vv;
    }
  }
}

// ---------------------------------------------------------------------------
// deconv_s2: ConvTranspose2d(k=4,s=2,p=1) via per-parity 2x2 s1 conv (fp32).
// ---------------------------------------------------------------------------
template <int CIN, int HIN, int COUT, bool RELU>
__global__ __launch_bounds__(256) void deconv_s2(
    const float* __restrict__ x, const float* __restrict__ w,
    const float* __restrict__ bias, float* __restrict__ y)
{
  constexpr int HOUT = HIN * 2;
  constexpr int TILES = HOUT / 8;
  __shared__ __align__(16) float Wl[16 * 4 * 68];
  __shared__ __align__(16) float Xl[4 * 48];
  __shared__ float bl[64];
  const int tid = threadIdx.x;
  const int wvid = tid >> 6;
  const int pr = wvid >> 1, pc = wvid & 1;
  const int lane = tid & 63;
  const int ty = lane >> 2, txv = lane & 3;
  const int r0 = (blockIdx.x / TILES) * 8, c0 = (blockIdx.x % TILES) * 8;
  const int a0 = r0 >> 1, b0 = c0 >> 1;
  const int oc0 = blockIdx.y * 64;
  const int n = blockIdx.z;
  if (tid < 64) bl[tid] = bias[oc0 + tid];
  const float* xn = x + (size_t)n * CIN * (HIN * HIN);
  float acc[4][4] = {};
  for (int ic0 = 0; ic0 < CIN; ic0 += 4) {
    __syncthreads();
#pragma unroll
    for (int it = 0; it < 4; ++it) {
      int i = tid + it * 256;
      int oc_l = i >> 4, r = i & 15;
      int ic_l = r >> 2, kh = r & 3;
      const float* wp = &w[((size_t)(oc0 + oc_l) * CIN + ic0 + ic_l) * 16 + kh * 4];
      float4 wv4 = *(const float4*)wp;
      float wa[4] = {wv4.x, wv4.y, wv4.z, wv4.w};
#pragma unroll
      for (int kw = 0; kw < 4; ++kw) {
        int kk = ic_l * 4 + (kh >> 1) * 2 + (kw >> 1);
        int par = (kh & 1) * 2 + (kw & 1);
        Wl[(kk * 4 + par) * 68 + oc_l] = wa[kw];
      }
    }
    for (int i = tid; i < 4 * 48; i += 256) {
      int ic_l = i / 48, rem = i - ic_l * 48;
      int rr = rem >> 3, cc = rem & 7;
      float v = 0.f;
      if (cc < 6) {
        int ih = a0 - 1 + rr, iw = b0 - 1 + cc;
        if ((unsigned)ih < (unsigned)HIN && (unsigned)iw < (unsigned)HIN)
          v = xn[(size_t)(ic0 + ic_l) * (HIN * HIN) + ih * HIN + iw];
      }
      Xl[i] = v;
    }
    __syncthreads();
#pragma unroll
    for (int ic_l = 0; ic_l < 4; ++ic_l) {
#pragma unroll
      for (int kk = 0; kk < 4; ++kk) {
        const int khp = kk >> 1, kwp = kk & 1;
        const int k = ic_l * 4 + kk;
        float4 a = *(const float4*)&Wl[(k * 4 + pr * 2 + pc) * 68 + ty * 4];
        const int xb = ic_l * 48 + (khp + pr) * 8 + txv + kwp + pc;
        float av[4] = {a.x, a.y, a.z, a.w};
        float bb[4] = {Xl[xb], Xl[xb + 8], Xl[xb + 16], Xl[xb + 24]};
#pragma unroll
        for (int i2 = 0; i2 < 4; ++i2)
#pragma unroll
          for (int u = 0; u < 4; ++u)
            acc[i2][u] = fmaf(av[i2], bb[u], acc[i2][u]);
      }
    }
  }
  float* yn = y + ((size_t)n * COUT + oc0) * (HOUT * HOUT);
#pragma unroll
  for (int i = 0; i < 4; ++i) {
    float bbias = bl[ty * 4 + i];
#pragma unroll
    for (int u = 0; u < 4; ++u) {
      float vv = acc[i][u] + bbias;
      if (RELU) vv = fmaxf(vv, 0.f);
      yn[(size_t)(ty * 4 + i) * (HOUT * HOUT) +
         (size_t)(r0 + 2 * u + pr) * HOUT + (c0 + 2 * txv + pc)] = vv;
    }
  }
}

// ---------------------------------------------------------------------------
// cb_convert: cb[8192*256] fp32 -> bf16 hi/lo (same [code][k] layout).
// ---------------------------------------------------------------------------
__global__ __launch_bounds__(256) void cb_convert(
    const float* __restrict__ cb, short* __restrict__ cbh, short* __restrict__ cbl)
{
  const int g = blockIdx.x * 256 + threadIdx.x;  // one per 8 floats
  const float* p = cb + (size_t)g * 8;
  short hs[8], ls[8];
#pragma unroll
  for (int u = 0; u < 8; ++u) {
    float v = p[u];
    short h = f2bf(v);
    hs[u] = h;
    ls[u] = f2bf(v - bf2f(h));
  }
  *(short8*)(cbh + (size_t)g * 8) = *(short8*)hs;
  *(short8*)(cbl + (size_t)g * 8) = *(short8*)ls;
}

// ---------------------------------------------------------------------------
// featT_prep: feat[16][256][1024] fp32 -> featT hi/lo bf16 [16*1024 tok][256 k]
// 64x64 LDS transpose tiles.
// ---------------------------------------------------------------------------
__global__ __launch_bounds__(256) void featT_prep(
    const float* __restrict__ feat, short* __restrict__ fth, short* __restrict__ ftl)
{
  __shared__ float T[64][65];
  const int b = blockIdx.z, k0 = blockIdx.y * 64, t0 = blockIdx.x * 64;
  const float* fb = feat + ((size_t)b * 256 + k0) * 1024 + t0;
  const int tid = threadIdx.x;
#pragma unroll
  for (int r = 0; r < 16; ++r) {
    int idx = r * 256 + tid;
    int kk = idx >> 6, tt = idx & 63;
    T[tt][kk] = fb[(size_t)kk * 1024 + tt];
  }
  __syncthreads();
#pragma unroll
  for (int r = 0; r < 2; ++r) {
    int i = r * 256 + tid;          // 0..511
    int tt = i >> 3, kg = i & 7;
    short hs[8], ls[8];
#pragma unroll
    for (int u = 0; u < 8; ++u) {
      float v = T[tt][kg * 8 + u];
      short h = f2bf(v);
      hs[u] = h;
      ls[u] = f2bf(v - bf2f(h));
    }
    size_t off = ((size_t)(b * 1024 + t0 + tt)) * 256 + k0 + kg * 8;
    *(short8*)(fth + off) = *(short8*)hs;
    *(short8*)(ftl + off) = *(short8*)ls;
  }
}

// ---------------------------------------------------------------------------
// vq_mfma: scores C[code][token] via bf16x3 MFMA; per-block top-2 per token.
// Block tile 128 codes x 128 tokens, wave tile 64x64, Kc=32.
// A = cb (hi/lo), B = featT (hi/lo); LDS layout [kg][row][8k] = 16B/entry.
// ---------------------------------------------------------------------------
__global__ __launch_bounds__(256) void vq_mfma(
    const short* __restrict__ cbh, const short* __restrict__ cbl,
    const short* __restrict__ fth, const short* __restrict__ ftl,
    float2* __restrict__ pval, int2* __restrict__ pidx)
{
  __shared__ __align__(16) short Ah[4 * 128 * 8];
  __shared__ __align__(16) short Al2[4 * 128 * 8];
  __shared__ __align__(16) short Bh[4 * 128 * 8];
  __shared__ __align__(16) short Bl2[4 * 128 * 8];
  const int tid = threadIdx.x;
  const int w = tid >> 6, lane = tid & 63;
  const int wm = w >> 1, wn = w & 1;
  const int tg = blockIdx.x, cg = blockIdx.y;
  const int code0 = cg * 128, tok0 = tg * 128;
  const int kgl = lane >> 4, cl = lane & 15;

  f32x4 acc[4][4];
#pragma unroll
  for (int i = 0; i < 4; ++i)
#pragma unroll
    for (int j = 0; j < 4; ++j) acc[i][j] = (f32x4){0.f, 0.f, 0.f, 0.f};

  const int i0 = w * 128;  // this wave's 128 staging entries (of 512)
  for (int kc = 0; kc < 256; kc += 32) {
    __syncthreads();
#pragma unroll
    for (int rep = 0; rep < 2; ++rep) {
      int ib = i0 + rep * 64;
      int i = ib + lane;
      int m = i & 127, kg = i >> 7;
      size_t goffA = (size_t)(code0 + m) * 256 + kc + kg * 8;
      size_t goffB = (size_t)(tok0 + m) * 256 + kc + kg * 8;
      int loff = ib * 8;  // shorts
      ld16(cbh + goffA, Ah + loff);
      ld16(cbl + goffA, Al2 + loff);
      ld16(fth + goffB, Bh + loff);
      ld16(ftl + goffB, Bl2 + loff);
    }
    __syncthreads();
    short8 ah[4], al[4], bh[4], bl[4];
#pragma unroll
    for (int mt = 0; mt < 4; ++mt) {
      int row = wm * 64 + mt * 16 + cl;
      ah[mt] = *(const short8*)&Ah[(kgl * 128 + row) * 8];
      al[mt] = *(const short8*)&Al2[(kgl * 128 + row) * 8];
    }
#pragma unroll
    for (int nt = 0; nt < 4; ++nt) {
      int row = wn * 64 + nt * 16 + cl;
      bh[nt] = *(const short8*)&Bh[(kgl * 128 + row) * 8];
      bl[nt] = *(const short8*)&Bl2[(kgl * 128 + row) * 8];
    }
#pragma unroll
    for (int mt = 0; mt < 4; ++mt)
#pragma unroll
      for (int nt = 0; nt < 4; ++nt) {
        acc[mt][nt] = __builtin_amdgcn_mfma_f32_16x16x32_bf16(
            ah[mt], bh[nt], acc[mt][nt], 0, 0, 0);
        acc[mt][nt] = __builtin_amdgcn_mfma_f32_16x16x32_bf16(
            ah[mt], bl[nt], acc[mt][nt], 0, 0, 0);
        acc[mt][nt] = __builtin_amdgcn_mfma_f32_16x16x32_bf16(
            al[mt], bh[nt], acc[mt][nt], 0, 0, 0);
      }
  }
  __syncthreads();

  // per-token top-2 over this block's 128 codes
  float* Sv = (float*)Ah;   // [2 wm][128 tl][2]
  int* Si = (int*)Bh;
#pragma unroll
  for (int nt = 0; nt < 4; ++nt) {
    float v1 = -3.4e38f, v2 = -3.4e38f;
    int j1 = 0, j2 = 0;
#pragma unroll
    for (int mt = 0; mt < 4; ++mt) {
      int cb2 = code0 + wm * 64 + mt * 16 + kgl * 4;
      f32x4 a = acc[mt][nt];
#pragma unroll
      for (int r = 0; r < 4; ++r) {
        float val = a[r];
        int code = cb2 + r;
        if (val > v1) { v2 = v1; j2 = j1; v1 = val; j1 = code; }
        else if (val > v2) { v2 = val; j2 = code; }
      }
    }
    for (int mk = 16; mk < 64; mk <<= 1) {
      float ov1 = __shfl_xor(v1, mk);
      int oj1 = __shfl_xor(j1, mk);
      float ov2 = __shfl_xor(v2, mk);
      int oj2 = __shfl_xor(j2, mk);
      if (ov1 > v1) {
        if (v1 >= ov2) { v2 = v1; j2 = j1; } else { v2 = ov2; j2 = oj2; }
        v1 = ov1; j1 = oj1;
      } else if (ov1 > v2) { v2 = ov1; j2 = oj1; }
    }
    if (lane < 16) {
      int tl = wn * 64 + nt * 16 + lane;
      Sv[(wm * 128 + tl) * 2 + 0] = v1;
      Sv[(wm * 128 + tl) * 2 + 1] = v2;
      Si[(wm * 128 + tl) * 2 + 0] = j1;
      Si[(wm * 128 + tl) * 2 + 1] = j2;
    }
  }
  __syncthreads();
  if (tid < 128) {
    int tl = tid;
    float v1 = Sv[tl * 2], v2 = Sv[tl * 2 + 1];
    int j1 = Si[tl * 2], j2 = Si[tl * 2 + 1];
    float ov1 = Sv[(128 + tl) * 2], ov2 = Sv[(128 + tl) * 2 + 1];
    int oj1 = Si[(128 + tl) * 2], oj2 = Si[(128 + tl) * 2 + 1];
    if (ov1 > v1) {
      if (v1 >= ov2) { v2 = v1; j2 = j1; } else { v2 = ov2; j2 = oj2; }
      v1 = ov1; j1 = oj1;
    } else if (ov1 > v2) { v2 = ov1; j2 = oj1; }
    size_t o = (size_t)cg * 16384 + tok0 + tl;
    pval[o] = make_float2(v1, v2);
    pidx[o] = make_int2(j1, j2);
  }
}

// ---------------------------------------------------------------------------
// vq_rescore: merge 64 block-partials -> top-4 approx candidates/token,
// rescore in exact fp32, emit final index (+float index output).
// ---------------------------------------------------------------------------
__global__ __launch_bounds__(256) void vq_rescore(
    const float2* __restrict__ pval, const int2* __restrict__ pidx,
    const float* __restrict__ feat, const float* __restrict__ cb,
    int* __restrict__ fidx, float* __restrict__ idx_out)
{
  const int t = blockIdx.x * 256 + threadIdx.x;  // 0..16383
  float vs[4] = {-3.4e38f, -3.4e38f, -3.4e38f, -3.4e38f};
  int is[4] = {0, 0, 0, 0};
  for (int cgi = 0; cgi < 64; ++cgi) {
    float2 pv = pval[(size_t)cgi * 16384 + t];
    int2 pi = pidx[(size_t)cgi * 16384 + t];
#pragma unroll
    for (int s = 0; s < 2; ++s) {
      float v = s ? pv.y : pv.x;
      int ii = s ? pi.y : pi.x;
      if (v > vs[3]) {
        vs[3] = v; is[3] = ii;
#pragma unroll
        for (int k = 3; k > 0; --k)
          if (vs[k] > vs[k - 1]) {
            float tv = vs[k]; vs[k] = vs[k - 1]; vs[k - 1] = tv;
            int ti = is[k]; is[k] = is[k - 1]; is[k - 1] = ti;
          }
      }
    }
  }
  const int b = t >> 10, tl = t & 1023;
  const float* fc = feat + (size_t)b * 262144 + tl;
  const float4* c0 = (const float4*)(cb + (size_t)is[0] * 256);
  const float4* c1 = (const float4*)(cb + (size_t)is[1] * 256);
  const float4* c2 = (const float4*)(cb + (size_t)is[2] * 256);
  const float4* c3 = (const float4*)(cb + (size_t)is[3] * 256);
  float s0 = 0.f, s1 = 0.f, s2 = 0.f, s3 = 0.f;
  for (int k4 = 0; k4 < 64; ++k4) {
    float f0 = fc[(size_t)(k4 * 4 + 0) * 1024];
    float f1 = fc[(size_t)(k4 * 4 + 1) * 1024];
    float f2 = fc[(size_t)(k4 * 4 + 2) * 1024];
    float f3 = fc[(size_t)(k4 * 4 + 3) * 1024];
    float4 w0 = c0[k4], w1 = c1[k4], w2 = c2[k4], w3 = c3[k4];
    s0 = fmaf(w0.x, f0, fmaf(w0.y, f1, fmaf(w0.z, f2, fmaf(w0.w, f3, s0))));
    s1 = fmaf(w1.x, f0, fmaf(w1.y, f1, fmaf(w1.z, f2, fmaf(w1.w, f3, s1))));
    s2 = fmaf(w2.x, f0, fmaf(w2.y, f1, fmaf(w2.z, f2, fmaf(w2.w, f3, s2))));
    s3 = fmaf(w3.x, f0, fmaf(w3.y, f1, fmaf(w3.z, f2, fmaf(w3.w, f3, s3))));
  }
  float best = s0; int bi = is[0];
  float sv[3] = {s1, s2, s3};
  int si2[3] = {is[1], is[2], is[3]};
#pragma unroll
  for (int c = 0; c < 3; ++c)
    if (sv[c] > best || (sv[c] == best && si2[c] < bi)) { best = sv[c]; bi = si2[c]; }
  fidx[t] = bi;
  idx_out[t] = (float)bi;
}

// ---------------------------------------------------------------------------
// gather2: build q[b][c][t] from final indices.
// ---------------------------------------------------------------------------
__global__ __launch_bounds__(256) void gather2(
    const float* __restrict__ cb, const int* __restrict__ fidx,
    float* __restrict__ q)
{
  __shared__ int sidx[64];
  const int tid = threadIdx.x;
  const int blk = blockIdx.x;
  const int b = blk >> 4, t0 = (blk & 15) * 64;
  if (tid < 64) sidx[tid] = fidx[b * 1024 + t0 + tid];
  __syncthreads();
  const int lane = tid & 63, cgq = tid >> 6;
  const int code = sidx[lane];
  const float* src = cb + (size_t)code * 256;
  float* dst = q + (size_t)b * 262144 + t0 + lane;
#pragma unroll
  for (int cc = 0; cc < 64; ++cc) {
    int c = cgq * 64 + cc;
    dst[(size_t)c * 1024] = src[c];
  }
}

// ---------------------------------------------------------------------------
// deconv3: [16,64,128,128] -> recon [16,3,256,256] (no ReLU).
// ---------------------------------------------------------------------------
__global__ __launch_bounds__(256) void deconv3_kernel(
    const float* __restrict__ x, const float* __restrict__ w,
    const float* __restrict__ bias, float* __restrict__ y)
{
  __shared__ __align__(16) float wl[4 * 3 * 64 * 4];
  const int tid = threadIdx.x;
  for (int i = tid; i < 3072; i += 256) {
    int oc = i >> 10, r = i & 1023, ic = r >> 4, tap = r & 15;
    int kh = tap >> 2, kw = tap & 3;
    int par = (kh & 1) * 2 + (kw & 1);
    int kidx = (kh >> 1) * 2 + (kw >> 1);
    wl[((par * 3 + oc) * 64 + ic) * 4 + kidx] = w[i];
  }
  __syncthreads();
  const int r = blockIdx.x, n = blockIdx.y, c = tid;
  const int pr = r & 1, pc = c & 1, par = pr * 2 + pc;
  const int a = r >> 1, bcol = c >> 1;
  const int ih0 = a - 1 + pr, iw0 = bcol - 1 + pc;
  const bool hv0 = (unsigned)ih0 < 128u, hv1 = (unsigned)(ih0 + 1) < 128u;
  const bool wv0 = (unsigned)iw0 < 128u, wv1 = (unsigned)(iw0 + 1) < 128u;
  const float* xn = x + (size_t)n * 64 * 16384;
  float acc0 = bias[0], acc1 = bias[1], acc2 = bias[2];
  const float* wp = &wl[par * 768];
  for (int ic = 0; ic < 64; ++ic) {
    const float* xr = xn + ic * 16384;
    float x00 = (hv0 && wv0) ? xr[ih0 * 128 + iw0] : 0.f;
    float x01 = (hv0 && wv1) ? xr[ih0 * 128 + iw0 + 1] : 0.f;
    float x10 = (hv1 && wv0) ? xr[(ih0 + 1) * 128 + iw0] : 0.f;
    float x11 = (hv1 && wv1) ? xr[(ih0 + 1) * 128 + iw0 + 1] : 0.f;
    float4 w0 = *(const float4*)&wp[(0 * 64 + ic) * 4];
    float4 w1 = *(const float4*)&wp[(1 * 64 + ic) * 4];
    float4 w2 = *(const float4*)&wp[(2 * 64 + ic) * 4];
    acc0 = fmaf(w0.x, x00, fmaf(w0.y, x01, fmaf(w0.z, x10, fmaf(w0.w, x11, acc0))));
    acc1 = fmaf(w1.x, x00, fmaf(w1.y, x01, fmaf(w1.z, x10, fmaf(w1.w, x11, acc1))));
    acc2 = fmaf(w2.x, x00, fmaf(w2.y, x01, fmaf(w2.z, x10, fmaf(w2.w, x11, acc2))));
  }
  float* yn = y + (size_t)n * 3 * 65536;
  yn[0 * 65536 + r * 256 + c] = acc0;
  yn[1 * 65536 + r * 256 + c] = acc1;
  yn[2 * 65536 + r * 256 + c] = acc2;
}

// ---------------------------------------------------------------------------
extern "C" void kernel_launch(void* const* d_in, const int* in_sizes, int n_in,
                              void* d_out, int out_size, void* d_ws, size_t ws_size,
                              hipStream_t stream)
{
  const float* x   = (const float*)d_in[0];
  const float* ew1 = (const float*)d_in[1];
  const float* eb1 = (const float*)d_in[2];
  const float* ew2 = (const float*)d_in[3];
  const float* eb2 = (const float*)d_in[4];
  const float* ew3 = (const float*)d_in[5];
  const float* eb3 = (const float*)d_in[6];
  const float* cb  = (const float*)d_in[7];
  const float* dw1 = (const float*)d_in[8];
  const float* db1 = (const float*)d_in[9];
  const float* dw2 = (const float*)d_in[10];
  const float* db2 = (const float*)d_in[11];
  const float* dw3 = (const float*)d_in[12];
  const float* db3 = (const float*)d_in[13];

  float* recon = (float*)d_out;
  float* idxf  = (float*)d_out + 3145728;

  char* ws = (char*)d_ws;
  // Workspace map (96 MiB total, liveness-aliased):
  float* h1   = (float*)ws;                       // [0,64M)  conv1 out
  float* h2   = (float*)(ws + 67108864);          // [64M,96M) conv2 out
  float* feat = (float*)ws;                       // [0,16M)  conv3 out (h1 dead)
  short* fth  = (short*)(ws + 16777216);          // [16M,24M)
  short* ftl  = (short*)(ws + 25165824);          // [24M,32M)
  short* cbh  = (short*)(ws + 33554432);          // [32M,36M)
  short* cbl  = (short*)(ws + 37748736);          // [36M,40M)
  float2* pval = (float2*)(ws + 41943040);        // [40M,48M)
  int2*   pidx = (int2*)(ws + 50331648);          // [48M,56M)
  int*    fidx = (int*)(ws + 58720256);           // [56M,+64K)
  float* q    = (float*)ws;                       // [0,16M)  (feat dead after rescore)
  float* d1   = (float*)(ws + 67108864);          // [64M,96M) (h2 dead)
  float* d2   = (float*)ws;                       // [0,64M)  (q dead after deconv1)

  conv1_kernel<<<dim3(64, 16), 256, 0, stream>>>(x, ew1, eb1, h1);
  conv_s2<64, 128, 128, true><<<dim3(64, 2, 16), 256, 0, stream>>>(h1, ew2, eb2, h2);
  conv_s2<128, 64, 256, false><<<dim3(16, 4, 16), 256, 0, stream>>>(h2, ew3, eb3, feat);

  cb_convert<<<dim3(1024), 256, 0, stream>>>(cb, cbh, cbl);
  featT_prep<<<dim3(16, 4, 16), 256, 0, stream>>>(feat, fth, ftl);
  vq_mfma<<<dim3(128, 64), 256, 0, stream>>>(cbh, cbl, fth, ftl, pval, pidx);
  vq_rescore<<<dim3(64), 256, 0, stream>>>(pval, pidx, feat, cb, fidx, idxf);
  gather2<<<dim3(256), 256, 0, stream>>>(cb, fidx, q);

  deconv_s2<256, 32, 128, true><<<dim3(64, 2, 16), 256, 0, stream>>>(q, dw1, db1, d1);
  deconv_s2<128, 64, 64, true><<<dim3(256, 1, 16), 256, 0, stream>>>(d1, dw2, db2, d2);
  deconv3_kernel<<<dim3(256, 16), 256, 0, stream>>>(d2, dw3, db3, recon);
}

// Round 3
// 1683.721 us; speedup vs baseline: 1.7586x; 1.3717x over previous
//
#include <hip/hip_runtime.h>
#include <hip/hip_fp16.h>
#include <cstdint>
#include <cstddef>

typedef __attribute__((ext_vector_type(8))) short short8;
typedef __attribute__((ext_vector_type(4))) float f32x4;

// bf16 helpers (RNE)
__device__ __forceinline__ short f2bf(float x) {
  union { float f; unsigned u; } a; a.f = x;
  unsigned r = a.u + 0x7fff + ((a.u >> 16) & 1);
  return (short)(r >> 16);
}
__device__ __forceinline__ float bf2f(short s) {
  union { unsigned u; float f; } a;
  a.u = ((unsigned)(unsigned short)s) << 16; return a.f;
}

// async global->LDS, 16B per lane; lds dest = wave-uniform base + lane*16
__device__ __forceinline__ void ld16(const void* g, void* l) {
  __builtin_amdgcn_global_load_lds(
      (const __attribute__((address_space(1))) unsigned int*)g,
      (__attribute__((address_space(3))) unsigned int*)l, 16, 0, 0);
}

// ---------------------------------------------------------------------------
// conv1: x[16,3,256,256] -> y[16,64,128,128], k=4 s=2 p=1, ReLU  (unchanged)
// ---------------------------------------------------------------------------
__global__ __launch_bounds__(256) void conv1_kernel(
    const float* __restrict__ x, const float* __restrict__ w,
    const float* __restrict__ bias, float* __restrict__ y)
{
  __shared__ __align__(16) float wl[64 * 48];
  __shared__ float bl[64];
  const int tid = threadIdx.x;
  for (int i = tid; i < 64 * 48; i += 256) wl[i] = w[i];
  if (tid < 64) bl[tid] = bias[tid];
  __syncthreads();
  const int n  = blockIdx.y;
  const int oh = blockIdx.x * 2 + (tid >> 7);
  const int ow = tid & 127;
  const float* xb = x + (size_t)n * 3 * 65536;
  const int ih0 = oh * 2 - 1, iw0 = ow * 2 - 1;
  float xin[48];
#pragma unroll
  for (int ic = 0; ic < 3; ++ic)
#pragma unroll
    for (int kh = 0; kh < 4; ++kh) {
      int ih = ih0 + kh;
      bool rok = (unsigned)ih < 256u;
#pragma unroll
      for (int kw = 0; kw < 4; ++kw) {
        int iw = iw0 + kw;
        xin[ic * 16 + kh * 4 + kw] =
            (rok && (unsigned)iw < 256u) ? xb[ic * 65536 + ih * 256 + iw] : 0.f;
      }
    }
  float* yb = y + (size_t)n * 64 * 16384 + oh * 128 + ow;
  for (int oc = 0; oc < 64; ++oc) {
    float acc = bl[oc];
    const float* wo = &wl[oc * 48];
#pragma unroll
    for (int j = 0; j < 48; ++j) acc = fmaf(wo[j], xin[j], acc);
    yb[(size_t)oc * 16384] = fmaxf(acc, 0.f);
  }
}

// ---------------------------------------------------------------------------
// conv_s2: k=4 s=2 p=1 implicit GEMM (fp32).  (unchanged)
// ---------------------------------------------------------------------------
template <int CIN, int HIN, int COUT, bool RELU>
__global__ __launch_bounds__(256) void conv_s2(
    const float* __restrict__ x, const float* __restrict__ w,
    const float* __restrict__ bias, float* __restrict__ y)
{
  constexpr int HOUT = HIN / 2;
  constexpr int TILES = HOUT / 8;
  __shared__ __align__(16) float Wl[64 * 68];
  __shared__ __align__(16) float Xl[4 * 342];
  __shared__ float bl[64];
  const int tid = threadIdx.x;
  const int tx = tid & 15, ty = tid >> 4;
  const int oh0 = (blockIdx.x / TILES) * 8, ow0 = (blockIdx.x % TILES) * 8;
  const int oc0 = blockIdx.y * 64;
  const int n = blockIdx.z;
  if (tid < 64) bl[tid] = bias[oc0 + tid];
  const float* xn = x + (size_t)n * CIN * (HIN * HIN);
  float acc[4][4] = {};
  int xoff[4];
#pragma unroll
  for (int q = 0; q < 4; ++q) {
    int p = tx + 16 * q;
    xoff[q] = (2 * (p >> 3)) * 19 + 2 * (p & 7);
  }
  const int ihb = 2 * oh0 - 1, iwb = 2 * ow0 - 1;
  for (int ic0 = 0; ic0 < CIN; ic0 += 4) {
    __syncthreads();
#pragma unroll
    for (int it = 0; it < 4; ++it) {
      int i = tid + it * 256;
      int oc_l = i >> 4, kq = i & 15;
      const float* wp = &w[((size_t)(oc0 + oc_l) * CIN + ic0) * 16 + kq * 4];
      float4 wv = *(const float4*)wp;
      Wl[(kq * 4 + 0) * 68 + oc_l] = wv.x;
      Wl[(kq * 4 + 1) * 68 + oc_l] = wv.y;
      Wl[(kq * 4 + 2) * 68 + oc_l] = wv.z;
      Wl[(kq * 4 + 3) * 68 + oc_l] = wv.w;
    }
    for (int i = tid; i < 4 * 342; i += 256) {
      int ic_l = i / 342, rem = i - ic_l * 342;
      int rr = rem / 19, cc = rem - rr * 19;
      int ih = ihb + rr, iw = iwb + cc;
      float v = 0.f;
      if ((unsigned)ih < (unsigned)HIN && (unsigned)iw < (unsigned)HIN)
        v = xn[(size_t)(ic0 + ic_l) * (HIN * HIN) + ih * HIN + iw];
      Xl[i] = v;
    }
    __syncthreads();
#pragma unroll
    for (int ic_l = 0; ic_l < 4; ++ic_l) {
#pragma unroll
      for (int tap = 0; tap < 16; ++tap) {
        const int k = ic_l * 16 + tap;
        const int kh = tap >> 2, kw = tap & 3;
        float4 a = *(const float4*)&Wl[k * 68 + ty * 4];
        const int base = ic_l * 342 + kh * 19 + kw;
        float av[4] = {a.x, a.y, a.z, a.w};
        float bb[4] = {Xl[base + xoff[0]], Xl[base + xoff[1]],
                       Xl[base + xoff[2]], Xl[base + xoff[3]]};
#pragma unroll
        for (int i2 = 0; i2 < 4; ++i2)
#pragma unroll
          for (int q = 0; q < 4; ++q)
            acc[i2][q] = fmaf(av[i2], bb[q], acc[i2][q]);
      }
    }
  }
  float* yn = y + ((size_t)n * COUT + oc0) * (HOUT * HOUT);
#pragma unroll
  for (int i = 0; i < 4; ++i) {
    float bbias = bl[ty * 4 + i];
#pragma unroll
    for (int q = 0; q < 4; ++q) {
      int p = tx + 16 * q;
      int u = p >> 3, v = p & 7;
      float vv = acc[i][q] + bbias;
      if (RELU) vv = fmaxf(vv, 0.f);
      yn[(size_t)(ty * 4 + i) * (HOUT * HOUT) + (oh0 + u) * HOUT + (ow0 + v)] = vv;
    }
  }
}

// ---------------------------------------------------------------------------
// cb_convert / featT_prep / vq_mfma / vq_rescore  (unchanged from round 2)
// ---------------------------------------------------------------------------
__global__ __launch_bounds__(256) void cb_convert(
    const float* __restrict__ cb, short* __restrict__ cbh, short* __restrict__ cbl)
{
  const int g = blockIdx.x * 256 + threadIdx.x;
  const float* p = cb + (size_t)g * 8;
  short hs[8], ls[8];
#pragma unroll
  for (int u = 0; u < 8; ++u) {
    float v = p[u];
    short h = f2bf(v);
    hs[u] = h;
    ls[u] = f2bf(v - bf2f(h));
  }
  *(short8*)(cbh + (size_t)g * 8) = *(short8*)hs;
  *(short8*)(cbl + (size_t)g * 8) = *(short8*)ls;
}

__global__ __launch_bounds__(256) void featT_prep(
    const float* __restrict__ feat, short* __restrict__ fth, short* __restrict__ ftl)
{
  __shared__ float T[64][65];
  const int b = blockIdx.z, k0 = blockIdx.y * 64, t0 = blockIdx.x * 64;
  const float* fb = feat + ((size_t)b * 256 + k0) * 1024 + t0;
  const int tid = threadIdx.x;
#pragma unroll
  for (int r = 0; r < 16; ++r) {
    int idx = r * 256 + tid;
    int kk = idx >> 6, tt = idx & 63;
    T[tt][kk] = fb[(size_t)kk * 1024 + tt];
  }
  __syncthreads();
#pragma unroll
  for (int r = 0; r < 2; ++r) {
    int i = r * 256 + tid;
    int tt = i >> 3, kg = i & 7;
    short hs[8], ls[8];
#pragma unroll
    for (int u = 0; u < 8; ++u) {
      float v = T[tt][kg * 8 + u];
      short h = f2bf(v);
      hs[u] = h;
      ls[u] = f2bf(v - bf2f(h));
    }
    size_t off = ((size_t)(b * 1024 + t0 + tt)) * 256 + k0 + kg * 8;
    *(short8*)(fth + off) = *(short8*)hs;
    *(short8*)(ftl + off) = *(short8*)ls;
  }
}

__global__ __launch_bounds__(256) void vq_mfma(
    const short* __restrict__ cbh, const short* __restrict__ cbl,
    const short* __restrict__ fth, const short* __restrict__ ftl,
    float2* __restrict__ pval, int2* __restrict__ pidx)
{
  __shared__ __align__(16) short Ah[4 * 128 * 8];
  __shared__ __align__(16) short Al2[4 * 128 * 8];
  __shared__ __align__(16) short Bh[4 * 128 * 8];
  __shared__ __align__(16) short Bl2[4 * 128 * 8];
  const int tid = threadIdx.x;
  const int w = tid >> 6, lane = tid & 63;
  const int wm = w >> 1, wn = w & 1;
  const int tg = blockIdx.x, cg = blockIdx.y;
  const int code0 = cg * 128, tok0 = tg * 128;
  const int kgl = lane >> 4, cl = lane & 15;

  f32x4 acc[4][4];
#pragma unroll
  for (int i = 0; i < 4; ++i)
#pragma unroll
    for (int j = 0; j < 4; ++j) acc[i][j] = (f32x4){0.f, 0.f, 0.f, 0.f};

  const int i0 = w * 128;
  for (int kc = 0; kc < 256; kc += 32) {
    __syncthreads();
#pragma unroll
    for (int rep = 0; rep < 2; ++rep) {
      int ib = i0 + rep * 64;
      int i = ib + lane;
      int m = i & 127, kg = i >> 7;
      size_t goffA = (size_t)(code0 + m) * 256 + kc + kg * 8;
      size_t goffB = (size_t)(tok0 + m) * 256 + kc + kg * 8;
      int loff = ib * 8;
      ld16(cbh + goffA, Ah + loff);
      ld16(cbl + goffA, Al2 + loff);
      ld16(fth + goffB, Bh + loff);
      ld16(ftl + goffB, Bl2 + loff);
    }
    __syncthreads();
    short8 ah[4], al[4], bh[4], bl[4];
#pragma unroll
    for (int mt = 0; mt < 4; ++mt) {
      int row = wm * 64 + mt * 16 + cl;
      ah[mt] = *(const short8*)&Ah[(kgl * 128 + row) * 8];
      al[mt] = *(const short8*)&Al2[(kgl * 128 + row) * 8];
    }
#pragma unroll
    for (int nt = 0; nt < 4; ++nt) {
      int row = wn * 64 + nt * 16 + cl;
      bh[nt] = *(const short8*)&Bh[(kgl * 128 + row) * 8];
      bl[nt] = *(const short8*)&Bl2[(kgl * 128 + row) * 8];
    }
#pragma unroll
    for (int mt = 0; mt < 4; ++mt)
#pragma unroll
      for (int nt = 0; nt < 4; ++nt) {
        acc[mt][nt] = __builtin_amdgcn_mfma_f32_16x16x32_bf16(
            ah[mt], bh[nt], acc[mt][nt], 0, 0, 0);
        acc[mt][nt] = __builtin_amdgcn_mfma_f32_16x16x32_bf16(
            ah[mt], bl[nt], acc[mt][nt], 0, 0, 0);
        acc[mt][nt] = __builtin_amdgcn_mfma_f32_16x16x32_bf16(
            al[mt], bh[nt], acc[mt][nt], 0, 0, 0);
      }
  }
  __syncthreads();

  float* Sv = (float*)Ah;
  int* Si = (int*)Bh;
#pragma unroll
  for (int nt = 0; nt < 4; ++nt) {
    float v1 = -3.4e38f, v2 = -3.4e38f;
    int j1 = 0, j2 = 0;
#pragma unroll
    for (int mt = 0; mt < 4; ++mt) {
      int cb2 = code0 + wm * 64 + mt * 16 + kgl * 4;
      f32x4 a = acc[mt][nt];
#pragma unroll
      for (int r = 0; r < 4; ++r) {
        float val = a[r];
        int code = cb2 + r;
        if (val > v1) { v2 = v1; j2 = j1; v1 = val; j1 = code; }
        else if (val > v2) { v2 = val; j2 = code; }
      }
    }
    for (int mk = 16; mk < 64; mk <<= 1) {
      float ov1 = __shfl_xor(v1, mk);
      int oj1 = __shfl_xor(j1, mk);
      float ov2 = __shfl_xor(v2, mk);
      int oj2 = __shfl_xor(j2, mk);
      if (ov1 > v1) {
        if (v1 >= ov2) { v2 = v1; j2 = j1; } else { v2 = ov2; j2 = oj2; }
        v1 = ov1; j1 = oj1;
      } else if (ov1 > v2) { v2 = ov1; j2 = oj1; }
    }
    if (lane < 16) {
      int tl = wn * 64 + nt * 16 + lane;
      Sv[(wm * 128 + tl) * 2 + 0] = v1;
      Sv[(wm * 128 + tl) * 2 + 1] = v2;
      Si[(wm * 128 + tl) * 2 + 0] = j1;
      Si[(wm * 128 + tl) * 2 + 1] = j2;
    }
  }
  __syncthreads();
  if (tid < 128) {
    int tl = tid;
    float v1 = Sv[tl * 2], v2 = Sv[tl * 2 + 1];
    int j1 = Si[tl * 2], j2 = Si[tl * 2 + 1];
    float ov1 = Sv[(128 + tl) * 2], ov2 = Sv[(128 + tl) * 2 + 1];
    int oj1 = Si[(128 + tl) * 2], oj2 = Si[(128 + tl) * 2 + 1];
    if (ov1 > v1) {
      if (v1 >= ov2) { v2 = v1; j2 = j1; } else { v2 = ov2; j2 = oj2; }
      v1 = ov1; j1 = oj1;
    } else if (ov1 > v2) { v2 = ov1; j2 = oj1; }
    size_t o = (size_t)cg * 16384 + tok0 + tl;
    pval[o] = make_float2(v1, v2);
    pidx[o] = make_int2(j1, j2);
  }
}

__global__ __launch_bounds__(256) void vq_rescore(
    const float2* __restrict__ pval, const int2* __restrict__ pidx,
    const float* __restrict__ feat, const float* __restrict__ cb,
    int* __restrict__ fidx, float* __restrict__ idx_out)
{
  const int t = blockIdx.x * 256 + threadIdx.x;
  float vs[4] = {-3.4e38f, -3.4e38f, -3.4e38f, -3.4e38f};
  int is[4] = {0, 0, 0, 0};
  for (int cgi = 0; cgi < 64; ++cgi) {
    float2 pv = pval[(size_t)cgi * 16384 + t];
    int2 pi = pidx[(size_t)cgi * 16384 + t];
#pragma unroll
    for (int s = 0; s < 2; ++s) {
      float v = s ? pv.y : pv.x;
      int ii = s ? pi.y : pi.x;
      if (v > vs[3]) {
        vs[3] = v; is[3] = ii;
#pragma unroll
        for (int k = 3; k > 0; --k)
          if (vs[k] > vs[k - 1]) {
            float tv = vs[k]; vs[k] = vs[k - 1]; vs[k - 1] = tv;
            int ti = is[k]; is[k] = is[k - 1]; is[k - 1] = ti;
          }
      }
    }
  }
  const int b = t >> 10, tl = t & 1023;
  const float* fc = feat + (size_t)b * 262144 + tl;
  const float4* c0 = (const float4*)(cb + (size_t)is[0] * 256);
  const float4* c1 = (const float4*)(cb + (size_t)is[1] * 256);
  const float4* c2 = (const float4*)(cb + (size_t)is[2] * 256);
  const float4* c3 = (const float4*)(cb + (size_t)is[3] * 256);
  float s0 = 0.f, s1 = 0.f, s2 = 0.f, s3 = 0.f;
  for (int k4 = 0; k4 < 64; ++k4) {
    float f0 = fc[(size_t)(k4 * 4 + 0) * 1024];
    float f1 = fc[(size_t)(k4 * 4 + 1) * 1024];
    float f2 = fc[(size_t)(k4 * 4 + 2) * 1024];
    float f3 = fc[(size_t)(k4 * 4 + 3) * 1024];
    float4 w0 = c0[k4], w1 = c1[k4], w2 = c2[k4], w3 = c3[k4];
    s0 = fmaf(w0.x, f0, fmaf(w0.y, f1, fmaf(w0.z, f2, fmaf(w0.w, f3, s0))));
    s1 = fmaf(w1.x, f0, fmaf(w1.y, f1, fmaf(w1.z, f2, fmaf(w1.w, f3, s1))));
    s2 = fmaf(w2.x, f0, fmaf(w2.y, f1, fmaf(w2.z, f2, fmaf(w2.w, f3, s2))));
    s3 = fmaf(w3.x, f0, fmaf(w3.y, f1, fmaf(w3.z, f2, fmaf(w3.w, f3, s3))));
  }
  float best = s0; int bi = is[0];
  float sv[3] = {s1, s2, s3};
  int si2[3] = {is[1], is[2], is[3]};
#pragma unroll
  for (int c = 0; c < 3; ++c)
    if (sv[c] > best || (sv[c] == best && si2[c] < bi)) { best = sv[c]; bi = si2[c]; }
  fidx[t] = bi;
  idx_out[t] = (float)bi;
}

// ---------------------------------------------------------------------------
// wpack: deconv weights -> Apack[par][oc][K], K=(kk*CIN+ic), bf16 hi/lo.
// value = w[oc][ic][2*khp+pr][2*kwp+pc], kk=khp*2+kwp (parity math verified R1).
// ---------------------------------------------------------------------------
template <int COUT, int CIN>
__global__ __launch_bounds__(256) void wpack(
    const float* __restrict__ w, short* __restrict__ Ah, short* __restrict__ Al)
{
  constexpr int K = 4 * CIN;
  const int idx = blockIdx.x * 256 + threadIdx.x;
  const int par = idx / (COUT * K);
  const int rem = idx % (COUT * K);
  const int oc = rem / K;
  const int k = rem % K;
  const int kk = k / CIN, ic = k % CIN;
  const int kh = 2 * (kk >> 1) + (par >> 1);
  const int kw = 2 * (kk & 1) + (par & 1);
  float v = w[(((size_t)oc * CIN + ic) * 4 + kh) * 4 + kw];
  short h = f2bf(v);
  Ah[idx] = h;
  Al[idx] = f2bf(v - bf2f(h));
}

// zero page for OOB-redirected global_load_lds (ws is re-poisoned each call)
__global__ __launch_bounds__(256) void zfill(float4* __restrict__ p) {
  p[threadIdx.x] = make_float4(0.f, 0.f, 0.f, 0.f);
}

// ---------------------------------------------------------------------------
// gather2: qT[token][ch] bf16 hi/lo = rows of cbh/cbl (pure row copy).
// ---------------------------------------------------------------------------
__global__ __launch_bounds__(256) void gather2(
    const short* __restrict__ cbh, const short* __restrict__ cbl,
    const int* __restrict__ fidx, short* __restrict__ qTh, short* __restrict__ qTl)
{
  const int tid = threadIdx.x;
  const int gt = blockIdx.x * 64 + (tid >> 2);
  const int part = tid & 3;
  const int code = fidx[gt];
  const short8* sh = (const short8*)(cbh + (size_t)code * 256 + part * 64);
  const short8* sl = (const short8*)(cbl + (size_t)code * 256 + part * 64);
  short8* dh = (short8*)(qTh + (size_t)gt * 256 + part * 64);
  short8* dl = (short8*)(qTl + (size_t)gt * 256 + part * 64);
#pragma unroll
  for (int j = 0; j < 8; ++j) { dh[j] = sh[j]; dl[j] = sl[j]; }
}

// ---------------------------------------------------------------------------
// deconv_mfma: ConvTranspose2d(k4,s2,p1)+ReLU as per-parity GEMM, bf16x3 MFMA.
// Input xT[n][pix][CIN] bf16 hi/lo. A = Apack[par][oc][K]. Per K-chunk (32 k's,
// single tap kk) B rows are pixels shifted by (dr,dc), OOB -> zero page.
// Block tile: (WM*64 oc) x (WN*64 px) = COUT x NPX; wave 64x64; vq_mfma pattern.
// Output: [n][outpix][COUT]; bf16 hi/lo (deconv1) or fp16 (deconv2).
// ---------------------------------------------------------------------------
template <int CIN, int GRID, int COUT, int NPX, int WM, int WN, bool OUT_HALF>
__global__ __launch_bounds__(256) void deconv_mfma(
    const short* __restrict__ inh, const short* __restrict__ inl,
    const short* __restrict__ Aph, const short* __restrict__ Apl,
    const float* __restrict__ bias, void* __restrict__ out_h,
    void* __restrict__ out_l, const short* __restrict__ zp)
{
  constexpr int K = 4 * CIN, HOUT = 2 * GRID, AE = 4 * COUT, BE = 4 * NPX;
  constexpr int GS = (GRID == 32) ? 5 : 6;
  __shared__ __align__(16) short AhL[AE * 8];
  __shared__ __align__(16) short AlL[AE * 8];
  __shared__ __align__(16) short BhL[BE * 8];
  __shared__ __align__(16) short BlL[BE * 8];
  __shared__ float bl[COUT];
  const int tid = threadIdx.x;
  const int w = tid >> 6, lane = tid & 63;
  const int wm = w / WN, wn = w % WN;
  const int kgl = lane >> 4, cl = lane & 15;
  const int par = blockIdx.y, n = blockIdx.z;
  const int pr = par >> 1, pc = par & 1;
  const int Ut0 = blockIdx.x * (NPX / GRID);
  if (tid < COUT) bl[tid] = bias[tid];

  f32x4 acc[4][4];
#pragma unroll
  for (int i = 0; i < 4; ++i)
#pragma unroll
    for (int j = 0; j < 4; ++j) acc[i][j] = (f32x4){0.f, 0.f, 0.f, 0.f};

  for (int kc = 0; kc < K; kc += 32) {
    const int kk = kc / CIN, ic0 = kc % CIN;
    const int dr = (kk >> 1) + pr - 1, dc = (kk & 1) + pc - 1;
    __syncthreads();
#pragma unroll
    for (int rep = 0; rep < AE / 256; ++rep) {
      int e = rep * 256 + tid;
      int kg = e / COUT, oc_l = e % COUT;
      size_t go = ((size_t)(par * COUT + oc_l)) * K + kc + kg * 8;
      int lo = (e & ~63) * 8;
      ld16(Aph + go, AhL + lo);
      ld16(Apl + go, AlL + lo);
    }
#pragma unroll
    for (int rep = 0; rep < BE / 256; ++rep) {
      int e = rep * 256 + tid;
      int kg = e / NPX, m = e % NPX;
      int sU = Ut0 + (m >> GS) + dr;
      int sV = (m & (GRID - 1)) + dc;
      bool ok = (unsigned)sU < (unsigned)GRID && (unsigned)sV < (unsigned)GRID;
      long pix = (long)(n * GRID + sU) * GRID + sV;
      size_t go = (size_t)(pix * CIN + ic0 + kg * 8);
      int lo = (e & ~63) * 8;
      ld16(ok ? inh + go : zp, BhL + lo);
      ld16(ok ? inl + go : zp, BlL + lo);
    }
    __syncthreads();
    short8 ah[4], al[4], bh[4], blo[4];
#pragma unroll
    for (int mt = 0; mt < 4; ++mt) {
      int row = kgl * COUT + wm * 64 + mt * 16 + cl;
      ah[mt] = *(const short8*)&AhL[row * 8];
      al[mt] = *(const short8*)&AlL[row * 8];
    }
#pragma unroll
    for (int nt = 0; nt < 4; ++nt) {
      int row = kgl * NPX + wn * 64 + nt * 16 + cl;
      bh[nt] = *(const short8*)&BhL[row * 8];
      blo[nt] = *(const short8*)&BlL[row * 8];
    }
#pragma unroll
    for (int mt = 0; mt < 4; ++mt)
#pragma unroll
      for (int nt = 0; nt < 4; ++nt) {
        acc[mt][nt] = __builtin_amdgcn_mfma_f32_16x16x32_bf16(
            ah[mt], bh[nt], acc[mt][nt], 0, 0, 0);
        acc[mt][nt] = __builtin_amdgcn_mfma_f32_16x16x32_bf16(
            ah[mt], blo[nt], acc[mt][nt], 0, 0, 0);
        acc[mt][nt] = __builtin_amdgcn_mfma_f32_16x16x32_bf16(
            al[mt], bh[nt], acc[mt][nt], 0, 0, 0);
      }
  }
  // C/D: oc = wm*64+mt*16+quad*4+reg, px = wn*64+nt*16+col (verified in vq_mfma)
#pragma unroll
  for (int mt = 0; mt < 4; ++mt) {
    const int oc = wm * 64 + mt * 16 + kgl * 4;
    const float4 bv = *(const float4*)&bl[oc];
#pragma unroll
    for (int nt = 0; nt < 4; ++nt) {
      const int px = wn * 64 + nt * 16 + cl;
      const int U = Ut0 + (px >> GS), V = px & (GRID - 1);
      const int r = 2 * U + pr, c = 2 * V + pc;
      const size_t ob = ((size_t)n * HOUT * HOUT + (size_t)r * HOUT + c) * COUT + oc;
      float v0 = fmaxf(acc[mt][nt][0] + bv.x, 0.f);
      float v1 = fmaxf(acc[mt][nt][1] + bv.y, 0.f);
      float v2 = fmaxf(acc[mt][nt][2] + bv.z, 0.f);
      float v3 = fmaxf(acc[mt][nt][3] + bv.w, 0.f);
      if constexpr (OUT_HALF) {
        ushort4 s;
        s.x = __half_as_ushort(__float2half(v0));
        s.y = __half_as_ushort(__float2half(v1));
        s.z = __half_as_ushort(__float2half(v2));
        s.w = __half_as_ushort(__float2half(v3));
        *(ushort4*)((unsigned short*)out_h + ob) = s;
      } else {
        short4 hh, ll;
        hh.x = f2bf(v0); ll.x = f2bf(v0 - bf2f(hh.x));
        hh.y = f2bf(v1); ll.y = f2bf(v1 - bf2f(hh.y));
        hh.z = f2bf(v2); ll.z = f2bf(v2 - bf2f(hh.z));
        hh.w = f2bf(v3); ll.w = f2bf(v3 - bf2f(hh.w));
        *(short4*)((short*)out_h + ob) = hh;
        *(short4*)((short*)out_l + ob) = ll;
      }
    }
  }
}

// ---------------------------------------------------------------------------
// deconv3: d2T[n][pix(128x128)][64] fp16 -> recon[16,3,256,256] (no ReLU).
// Block = 8x32 output px (one n); wave = one parity (uniform weight reads).
// Xl padded to 68 (2-way banks only); wl[par][kidx][oc][ic].
// ---------------------------------------------------------------------------
__global__ __launch_bounds__(256) void deconv3_kernel(
    const __half* __restrict__ d2, const float* __restrict__ w,
    const float* __restrict__ bias, float* __restrict__ y)
{
  __shared__ __align__(16) float Xl[108 * 68];
  __shared__ __align__(16) float wl[4 * 4 * 3 * 64];
  const int tid = threadIdx.x;
  for (int i = tid; i < 3072; i += 256) {
    int oc = i >> 10, ic = (i >> 4) & 63, kh = (i >> 2) & 3, kw = i & 3;
    int par = (kh & 1) * 2 + (kw & 1), kidx = (kh >> 1) * 2 + (kw >> 1);
    wl[((par * 4 + kidx) * 3 + oc) * 64 + ic] = w[i];
  }
  const int n = blockIdx.z, r0 = blockIdx.y * 8, c0 = blockIdx.x * 32;
  const int gr0 = (r0 >> 1) - 1, gc0 = (c0 >> 1) - 1;
  for (int e = tid; e < 1728; e += 256) {
    int pl = e >> 4, sub = e & 15;
    int rr = pl / 18, cc = pl - rr * 18;
    int gr = gr0 + rr, gc = gc0 + cc;
    float4 v = make_float4(0.f, 0.f, 0.f, 0.f);
    if ((unsigned)gr < 128u && (unsigned)gc < 128u) {
      const __half2* p =
          (const __half2*)(d2 + ((size_t)(n * 16384 + gr * 128 + gc) * 64 + sub * 4));
      float2 f0 = __half22float2(p[0]);
      float2 f1 = __half22float2(p[1]);
      v = make_float4(f0.x, f0.y, f1.x, f1.y);
    }
    *(float4*)&Xl[pl * 68 + sub * 4] = v;
  }
  __syncthreads();
  const int wv = tid >> 6, lane = tid & 63;
  const int pr = wv >> 1, pc = wv & 1;
  const int Ul = lane >> 4, Vl = lane & 15;
  float a0 = bias[0], a1 = bias[1], a2 = bias[2];
  const int parb = wv * 768;  // ((par*4+kidx)*3+oc)*64 base
#pragma unroll
  for (int ic4 = 0; ic4 < 16; ++ic4) {
    float4 xv[4];
#pragma unroll
    for (int t = 0; t < 4; ++t) {
      int lr = Ul + (t >> 1) + pr, lc = Vl + (t & 1) + pc;
      xv[t] = *(const float4*)&Xl[(lr * 18 + lc) * 68 + ic4 * 4];
    }
#pragma unroll
    for (int t = 0; t < 4; ++t) {
      float4 w0 = *(const float4*)&wl[parb + (t * 3 + 0) * 64 + ic4 * 4];
      float4 w1 = *(const float4*)&wl[parb + (t * 3 + 1) * 64 + ic4 * 4];
      float4 w2 = *(const float4*)&wl[parb + (t * 3 + 2) * 64 + ic4 * 4];
      a0 = fmaf(w0.x, xv[t].x, fmaf(w0.y, xv[t].y, fmaf(w0.z, xv[t].z, fmaf(w0.w, xv[t].w, a0))));
      a1 = fmaf(w1.x, xv[t].x, fmaf(w1.y, xv[t].y, fmaf(w1.z, xv[t].z, fmaf(w1.w, xv[t].w, a1))));
      a2 = fmaf(w2.x, xv[t].x, fmaf(w2.y, xv[t].y, fmaf(w2.z, xv[t].z, fmaf(w2.w, xv[t].w, a2))));
    }
  }
  const int r = r0 + 2 * Ul + pr, c = c0 + 2 * Vl + pc;
  float* yn = y + (size_t)n * 3 * 65536 + r * 256 + c;
  yn[0] = a0;
  yn[65536] = a1;
  yn[131072] = a2;
}

// ---------------------------------------------------------------------------
extern "C" void kernel_launch(void* const* d_in, const int* in_sizes, int n_in,
                              void* d_out, int out_size, void* d_ws, size_t ws_size,
                              hipStream_t stream)
{
  const float* x   = (const float*)d_in[0];
  const float* ew1 = (const float*)d_in[1];
  const float* eb1 = (const float*)d_in[2];
  const float* ew2 = (const float*)d_in[3];
  const float* eb2 = (const float*)d_in[4];
  const float* ew3 = (const float*)d_in[5];
  const float* eb3 = (const float*)d_in[6];
  const float* cb  = (const float*)d_in[7];
  const float* dw1 = (const float*)d_in[8];
  const float* db1 = (const float*)d_in[9];
  const float* dw2 = (const float*)d_in[10];
  const float* db2 = (const float*)d_in[11];
  const float* dw3 = (const float*)d_in[12];
  const float* db3 = (const float*)d_in[13];

  float* recon = (float*)d_out;
  float* idxf  = (float*)d_out + 3145728;

  char* ws = (char*)d_ws;
  // Workspace map (max 96 MiB, liveness-aliased):
  float* h1   = (float*)ws;                       // [0,64M)   conv1 out
  float* h2   = (float*)(ws + 67108864);          // [64M,96M) conv2 out
  float* feat = (float*)ws;                       // [0,16M)   conv3 out (h1 dead)
  short* fth  = (short*)(ws + 16777216);          // [16M,24M)
  short* ftl  = (short*)(ws + 25165824);          // [24M,32M)
  short* cbh  = (short*)(ws + 33554432);          // [32M,36M)
  short* cbl  = (short*)(ws + 37748736);          // [36M,40M)
  float2* pval = (float2*)(ws + 41943040);        // [40M,48M)
  int2*   pidx = (int2*)(ws + 50331648);          // [48M,56M)
  int*    fidx = (int*)(ws + 58720256);           // [56M,+64K)
  // after vq_rescore (pval/pidx dead):
  short* A1h = (short*)(ws + 50331648);           // 1 MB  (pidx region)
  short* A1l = (short*)(ws + 51380224);           // 1 MB
  short* A2h = (short*)(ws + 52428800);           // 256 KB
  short* A2l = (short*)(ws + 52690944);           // 256 KB
  short* zp  = (short*)(ws + 52953088);           // 4 KB zero page
  short* qTh = (short*)ws;                        // [0,8M)   (feat dead)
  short* qTl = (short*)(ws + 8388608);            // [8M,16M)
  short* d1h = (short*)(ws + 67108864);           // [64M,80M)  (h2 dead)
  short* d1l = (short*)(ws + 83886080);           // [80M,96M)
  __half* d2 = (__half*)ws;                       // [0,32M)  fp16 (qT/fth/ftl dead)

  conv1_kernel<<<dim3(64, 16), 256, 0, stream>>>(x, ew1, eb1, h1);
  conv_s2<64, 128, 128, true><<<dim3(64, 2, 16), 256, 0, stream>>>(h1, ew2, eb2, h2);
  conv_s2<128, 64, 256, false><<<dim3(16, 4, 16), 256, 0, stream>>>(h2, ew3, eb3, feat);

  cb_convert<<<dim3(1024), 256, 0, stream>>>(cb, cbh, cbl);
  featT_prep<<<dim3(16, 4, 16), 256, 0, stream>>>(feat, fth, ftl);
  vq_mfma<<<dim3(128, 64), 256, 0, stream>>>(cbh, cbl, fth, ftl, pval, pidx);
  vq_rescore<<<dim3(64), 256, 0, stream>>>(pval, pidx, feat, cb, fidx, idxf);

  wpack<128, 256><<<dim3(2048), 256, 0, stream>>>(dw1, A1h, A1l);
  wpack<64, 128><<<dim3(512), 256, 0, stream>>>(dw2, A2h, A2l);
  zfill<<<dim3(1), 256, 0, stream>>>((float4*)zp);
  gather2<<<dim3(256), 256, 0, stream>>>(cbh, cbl, fidx, qTh, qTl);

  deconv_mfma<256, 32, 128, 128, 2, 2, false>
      <<<dim3(8, 4, 16), 256, 0, stream>>>(qTh, qTl, A1h, A1l, db1, d1h, d1l, zp);
  deconv_mfma<128, 64, 64, 256, 1, 4, true>
      <<<dim3(16, 4, 16), 256, 0, stream>>>(d1h, d1l, A2h, A2l, db2, d2, d2, zp);
  deconv3_kernel<<<dim3(8, 32, 16), 256, 0, stream>>>(d2, dw3, db3, recon);
}